// Round 2
// baseline (968.258 us; speedup 1.0000x reference)
//
#include <hip/hip_runtime.h>
#include <hip/hip_bf16.h>
#include <cstdint>
#include <math.h>

#define N_EMB   65536
#define N_PROTO 2048
#define DIM     512

// Single fused kernel: no workspace, no inter-kernel dataflow (round-1's
// 3-kernel pipeline diverged on replays: stale/poisoned ws lines across
// per-XCD L2s). Everything — fp32->bf16 convert, row norms, MFMA GEMM,
// -sqrt epilogue — happens inside one block.

typedef __bf16 bf16x8 __attribute__((ext_vector_type(8)));
typedef float  f32x4  __attribute__((ext_vector_type(4)));

__device__ inline bf16x8 cvt8(float4 u, float4 v) {
    bf16x8 r;
    r[0] = (__bf16)u.x; r[1] = (__bf16)u.y; r[2] = (__bf16)u.z; r[3] = (__bf16)u.w;
    r[4] = (__bf16)v.x; r[5] = (__bf16)v.y; r[6] = (__bf16)v.z; r[7] = (__bf16)v.w;
    return r;
}
__device__ inline float dot4(float4 a) { return a.x*a.x + a.y*a.y + a.z*a.z + a.w*a.w; }

// 128x128 output tile, BK=32. Block 256 = 4 waves (2x2), wave tile 64x64 =
// 4x4 of mfma_f32_16x16x32_bf16. LDS tiles are bf16 with 64 B row stride —
// fragment-read pattern identical to the m97-validated structure.
__global__ __launch_bounds__(256) void fused_kernel(const float* __restrict__ E,
                                                    const float* __restrict__ Pm,
                                                    float* __restrict__ out) {
    __shared__ __align__(16) __bf16 sA[128 * 32];
    __shared__ __align__(16) __bf16 sB[128 * 32];
    __shared__ __align__(16) float ldsXsq[128];
    __shared__ __align__(16) float ldsPsq[128];

    const int tid   = threadIdx.x;
    const int wave  = tid >> 6, lane = tid & 63;
    const int wm    = wave >> 1, wn = wave & 1;
    const int laneM = lane & 15, laneQ = lane >> 4;

    const int rowBase = blockIdx.y * 128;
    const int colBase = blockIdx.x * 128;

    // Staging identity: each wave stages rows [wave*32, wave*32+32) of both
    // tiles; lane -> (row = wave*32 + lane/2, half h = lane&1 of 32 floats).
    const int rL   = lane >> 1;
    const int h    = lane & 1;
    const int sRow = wave * 32 + rL;
    const float* gA = E  + (size_t)(rowBase + sRow) * DIM + h * 16;
    const float* gB = Pm + (size_t)(colBase + sRow) * DIM + h * 16;
    __bf16* wA = sA + sRow * 32 + h * 16;
    __bf16* wB = sB + sRow * 32 + h * 16;

    // Preload K-tile 0 into registers.
    float4 a0 = *(const float4*)(gA + 0), a1 = *(const float4*)(gA + 4);
    float4 a2 = *(const float4*)(gA + 8), a3 = *(const float4*)(gA + 12);
    float4 b0 = *(const float4*)(gB + 0), b1 = *(const float4*)(gB + 4);
    float4 b2 = *(const float4*)(gB + 8), b3 = *(const float4*)(gB + 12);

    float ssqA = 0.0f, ssqB = 0.0f;   // fp32-exact row norms from staging regs
    f32x4 acc[4][4] = {};

    #pragma unroll 1
    for (int kt = 0; kt < DIM / 32; ++kt) {
        // Convert + norm-accumulate + stage to LDS (bf16, 2 x 16 B per matrix).
        ssqA += dot4(a0) + dot4(a1) + dot4(a2) + dot4(a3);
        ssqB += dot4(b0) + dot4(b1) + dot4(b2) + dot4(b3);
        *(bf16x8*)(wA)     = cvt8(a0, a1);
        *(bf16x8*)(wA + 8) = cvt8(a2, a3);
        *(bf16x8*)(wB)     = cvt8(b0, b1);
        *(bf16x8*)(wB + 8) = cvt8(b2, b3);
        __syncthreads();                       // staging visible to all waves

        // Prefetch next K-tile: in flight across the whole MFMA phase.
        if (kt != DIM / 32 - 1) {
            const float* nA = gA + (kt + 1) * 32;
            const float* nB = gB + (kt + 1) * 32;
            a0 = *(const float4*)(nA + 0); a1 = *(const float4*)(nA + 4);
            a2 = *(const float4*)(nA + 8); a3 = *(const float4*)(nA + 12);
            b0 = *(const float4*)(nB + 0); b1 = *(const float4*)(nB + 4);
            b2 = *(const float4*)(nB + 8); b3 = *(const float4*)(nB + 12);
        }

        bf16x8 af[4], bfr[4];
        #pragma unroll
        for (int mi = 0; mi < 4; ++mi)
            af[mi] = *(const bf16x8*)(sA + (wm*64 + mi*16 + laneM) * 32 + laneQ * 8);
        #pragma unroll
        for (int ni = 0; ni < 4; ++ni)
            bfr[ni] = *(const bf16x8*)(sB + (wn*64 + ni*16 + laneM) * 32 + laneQ * 8);
        #pragma unroll
        for (int mi = 0; mi < 4; ++mi)
            #pragma unroll
            for (int ni = 0; ni < 4; ++ni)
                acc[mi][ni] = __builtin_amdgcn_mfma_f32_16x16x32_bf16(af[mi], bfr[ni], acc[mi][ni], 0, 0, 0);
        __syncthreads();                       // frag reads done before next stage
    }

    // Redistribute row norms through LDS: halves h=0,1 of each row combine.
    {
        const float vA = ssqA + __shfl_xor(ssqA, 1);
        const float vB = ssqB + __shfl_xor(ssqB, 1);
        if (h == 0) { ldsXsq[sRow] = vA; ldsPsq[sRow] = vB; }
    }
    __syncthreads();

    // Epilogue: C/D layout col = lane&15, row = laneQ*4 + reg (m89-verified).
    #pragma unroll
    for (int mi = 0; mi < 4; ++mi) {
        const int rm0 = wm*64 + mi*16 + laneQ*4;
        const float4 xs = *(const float4*)(ldsXsq + rm0);
        #pragma unroll
        for (int ni = 0; ni < 4; ++ni) {
            const int cn = wn*64 + ni*16 + laneM;
            const float pq = ldsPsq[cn];
            float* o = out + (size_t)(rowBase + rm0) * N_PROTO + (colBase + cn);
            const f32x4 c = acc[mi][ni];
            o[0 * N_PROTO] = -sqrtf(fmaxf(xs.x - 2.0f * c[0] + pq, 0.0f));
            o[1 * N_PROTO] = -sqrtf(fmaxf(xs.y - 2.0f * c[1] + pq, 0.0f));
            o[2 * N_PROTO] = -sqrtf(fmaxf(xs.z - 2.0f * c[2] + pq, 0.0f));
            o[3 * N_PROTO] = -sqrtf(fmaxf(xs.w - 2.0f * c[3] + pq, 0.0f));
        }
    }
}

extern "C" void kernel_launch(void* const* d_in, const int* in_sizes, int n_in,
                              void* d_out, int out_size, void* d_ws, size_t ws_size,
                              hipStream_t stream) {
    const float* emb = (const float*)d_in[0];
    const float* pro = (const float*)d_in[1];
    float* out = (float*)d_out;
    (void)d_ws; (void)ws_size; (void)in_sizes; (void)n_in; (void)out_size;

    fused_kernel<<<dim3(N_PROTO / 128, N_EMB / 128), 256, 0, stream>>>(emb, pro, out);
}